// Round 13
// baseline (181.601 us; speedup 1.0000x reference)
//
#include <hip/hip_runtime.h>

typedef __fp16 h2 __attribute__((ext_vector_type(2)));

constexpr int VIEWS = 360;
constexpr int IMGSZ = 512;
constexpr int WCHUNK = 64;   // w per block
constexpr int KH = 40;       // h per chunk (R12-validated dbuf geometry)
constexpr int PITCH = 84;    // dwords per LDS row
constexpr int NXF4 = 21;     // 16B groups per row
constexpr int MAXNY = 79;    // rows bound: ceil(sqrt(63^2+39^2))+4
constexpr int TDW = PITCH * MAXNY;   // 6636 dw = 26544 B per buffer
constexpr int PW = 712;      // padded width (dwords per row)
constexpr int PH = 704;      // padded height
constexpr int PAD = 96;
constexpr int NT = 512;      // 8 waves/block; 3 blocks/CU -> 24 waves/CU

// Async global->LDS 16B copy (R1/R12-validated). Dest = uniform + lane*16.
#define ASYNC_CP16(SRC, DST)                                              \
    __builtin_amdgcn_global_load_lds(                                     \
        (const __attribute__((address_space(1))) unsigned*)(SRC),         \
        (__attribute__((address_space(3))) unsigned*)(DST), 16, 0, 0)

// ---------- pad kernel: zero-padded, BATCH-PACKED f16 texels ---------------
__global__ __launch_bounds__(256) void pad_kernel(const float* __restrict__ x,
                                                  unsigned* __restrict__ padq) {
    constexpr int PW4 = PW / 4;              // 178 groups per row
    constexpr int total = PH * PW4;          // 125312 groups
    int idx = blockIdx.x * 256 + threadIdx.x;
    if (idx >= total) return;
    int py = idx / PW4;
    int px4 = idx - py * PW4;
    int gx = px4 * 4 - PAD;                  // multiple of 4
    int gy = py - PAD;
    const float* img0 = x;
    const float* img1 = x + (size_t)IMGSZ * IMGSZ;
    float4 a = make_float4(0.f, 0.f, 0.f, 0.f);
    float4 bq = a;
    if ((unsigned)gy < (unsigned)IMGSZ && (unsigned)gx < (unsigned)IMGSZ) {
        size_t off = (size_t)gy * IMGSZ + gx;    // gx%4==0 -> all-in/all-out
        a  = *(const float4*)(img0 + off);
        bq = *(const float4*)(img1 + off);
    }
    uint4 d;
    d.x = __builtin_bit_cast(unsigned, __builtin_amdgcn_cvt_pkrtz(a.x, bq.x));
    d.y = __builtin_bit_cast(unsigned, __builtin_amdgcn_cvt_pkrtz(a.y, bq.y));
    d.z = __builtin_bit_cast(unsigned, __builtin_amdgcn_cvt_pkrtz(a.z, bq.z));
    d.w = __builtin_bit_cast(unsigned, __builtin_amdgcn_cvt_pkrtz(a.w, bq.w));
    *(uint4*)&padq[(size_t)idx * 4] = d;
}

// ---------- main kernel: dbuf pipeline + hoisted offsets + incr. bbox ------
__global__ __launch_bounds__(NT, 4) void fp_kernel(const unsigned* __restrict__ padq,
                                                   float* __restrict__ out) {
    __shared__ __align__(16) unsigned bufA[TDW];
    __shared__ __align__(16) unsigned bufB[TDW];

    int blk = blockIdx.x;          // 2880 = VIEWS * 8
    int wc = blk & 7;
    int v = blk >> 3;

    int tid = threadIdx.x;
    int lane = tid & 63;
    int p = tid >> 6;              // h phase 0..7
    int w = wc * WCHUNK + lane;

    double ang = -3.14159265358979323846 * (double)(v + 1) / (double)VIEWS
                 - 3.14159265358979323846;
    float c = (float)cos(ang);
    float s = (float)sin(ang);

    float xw = (float)w + 0.5f - 256.0f;
    float cxw = fmaf(c, xw, 255.5f);
    float sxw = fmaf(s, xw, 255.5f);

    // Chunk-invariant staging offsets: job k's (row, colgroup) depends only
    // on (tid, k). goff = dword offset from the chunk's base pointer.
    int goff[4];
    #pragma unroll
    for (int k = 0; k < 4; ++k) {
        int i = (k << 9) + tid;
        int ry = i / NXF4;                 // const magic-mul (once)
        int rx = i - ry * NXF4;
        goff[k] = ry * PW + (rx << 2);
    }

    // Per-thread valid-h interval (validated rounds 0-12).
    float lo = -1e30f, hi = 1e30f;
    {
        float coef = -s, base = cxw;
        if (fabsf(coef) > 1e-6f) {
            float a = (-1.0f - base) / coef;
            float bq = (512.0f - base) / coef;
            lo = fmaxf(lo, fminf(a, bq));
            hi = fminf(hi, fmaxf(a, bq));
        } else if (!(base > -1.0f && base < 512.0f)) {
            lo = 1e30f; hi = -1e30f;
        }
    }
    {
        float coef = c, base = sxw;
        if (fabsf(coef) > 1e-6f) {
            float a = (-1.0f - base) / coef;
            float bq = (512.0f - base) / coef;
            lo = fmaxf(lo, fminf(a, bq));
            hi = fminf(hi, fmaxf(a, bq));
        } else if (!(base > -1.0f && base < 512.0f)) {
            lo = 1e30f; hi = -1e30f;
        }
    }
    float h0f = fminf(fmaxf(floorf(lo + 255.5f) - 1.0f, 0.0f), 512.0f);
    float h1f = fminf(fmaxf(ceilf(hi + 255.5f) + 1.0f, -1.0f), 511.0f);
    int h0 = (int)h0f;
    int h1 = (int)h1f;

    int bh0 = h0, bh1 = h1;
    #pragma unroll
    for (int m = 1; m < 64; m <<= 1) {
        bh0 = min(bh0, __shfl_xor(bh0, m, 64));
        bh1 = max(bh1, __shfl_xor(bh1, m, 64));
    }

    float xa = (float)(wc * WCHUNK) + 0.5f - 256.0f;
    float xb = xa + 63.0f;
    float xlo_pair = fminf(c * xa, c * xb);      // view-constant (hoisted)
    float ylo_pair = fminf(s * xa, s * xb);
    float yhi_pair = fmaxf(s * xa, s * xb);

    float acc0 = 0.0f, acc1 = 0.0f;
    float step8x = -8.0f * s;
    float step8y = 8.0f * c;

    // Incremental bbox state for the NEXT chunk to derive (starts at bh0).
    float ixmn = 0.f, iymn = 0.f, iymx = 0.f;

// Derive (X4,YL,T4) for chunk HC from incremental state; advance state by KH.
// Last (clamped) chunk recomputes exactly -> staging stays inside padq.
#define BBOX2(HC, X4, YL, T4)                                               \
    {                                                                       \
        float bxmn_, bymn_, bymx_;                                          \
        if ((HC) + KH - 1 <= bh1) {                                         \
            bxmn_ = ixmn; bymn_ = iymn; bymx_ = iymx;                       \
        } else {                                                            \
            float ha_ = (float)(HC) - 255.5f;                               \
            float hb_ = (float)bh1 - 255.5f;                                \
            bxmn_ = xlo_pair - fmaxf(s * ha_, s * hb_) + 255.5f;            \
            bymn_ = ylo_pair + fminf(c * ha_, c * hb_) + 255.5f;            \
            bymx_ = yhi_pair + fmaxf(c * ha_, c * hb_) + 255.5f;            \
        }                                                                   \
        X4 = ((int)floorf(bxmn_) - 1) & ~3;                                 \
        YL = (int)floorf(bymn_) - 1;                                        \
        int NY_ = min((int)floorf(bymx_) + 3 - (YL), MAXNY);                \
        T4 = NY_ * NXF4;                                                    \
        ixmn -= s * (float)KH;                                              \
        iymn += c * (float)KH;                                              \
        iymx += c * (float)KH;                                              \
    }

// Issue async staging of chunk (X4,YL,T4) into BUF (no waits here).
#define STAGE(BUF, X4, YL, T4)                                              \
    {                                                                       \
        const unsigned* pb_ = padq + ((YL) + PAD) * PW + ((X4) + PAD);      \
        _Pragma("unroll")                                                   \
        for (int k_ = 0; k_ < 4; ++k_) {                                    \
            int i_ = (k_ << 9) + tid;                                       \
            if (((k_ << 9) + (p << 6) + 63) < (T4)) {                       \
                ASYNC_CP16(pb_ + goff[k_], &BUF[i_ << 2]);                  \
            } else if (i_ < (T4)) {                                         \
                uint4 val_ = *(const uint4*)(pb_ + goff[k_]);               \
                *(uint4*)&BUF[i_ << 2] = val_;                              \
            }                                                               \
        }                                                                   \
    }

// Gather chunk HC from BUF using its (X4,YL); wave p takes h = HC+p, +8, ...
#define GATHER(BUF, HC, X4, YL)                                             \
    {                                                                       \
        int hend_ = min((HC) + KH - 1, bh1);                                \
        float hh0_ = (float)((HC) + p) - 255.5f;                            \
        float ixr_ = fmaf(-s, hh0_, cxw) - (float)(X4);                     \
        float iyr_ = fmaf(c, hh0_, sxw) - (float)(YL);                      \
        h2 a0_ = (h2)0.0f, a1_ = (h2)0.0f;                                  \
        int par_ = 0;                                                       \
        _Pragma("unroll 5")                                                 \
        for (int h_ = (HC) + p; h_ <= hend_; h_ += 8) {                     \
            float tx_ = truncf(ixr_);                                       \
            float ty_ = truncf(iyr_);                                       \
            float wx_ = ixr_ - tx_;                                         \
            float wy_ = iyr_ - ty_;                                         \
            h2 wxs_ = __builtin_amdgcn_cvt_pkrtz(wx_, wx_);                 \
            h2 wys_ = __builtin_amdgcn_cvt_pkrtz(wy_, wy_);                 \
            unsigned a_ = (unsigned)fmaf(ty_, 336.0f, tx_ * 4.0f);          \
            const unsigned* pt_ =                                           \
                (const unsigned*)((const char*)BUF + a_);                   \
            h2 t00_ = __builtin_bit_cast(h2, pt_[0]);                       \
            h2 t01_ = __builtin_bit_cast(h2, pt_[1]);                       \
            h2 t10_ = __builtin_bit_cast(h2, pt_[PITCH]);                   \
            h2 t11_ = __builtin_bit_cast(h2, pt_[PITCH + 1]);               \
            h2 r0_ = t00_ + (t01_ - t00_) * wxs_;                           \
            h2 r1_ = t10_ + (t11_ - t10_) * wxs_;                           \
            h2 ct_ = r0_ + (r1_ - r0_) * wys_;                              \
            if (par_) a1_ += ct_; else a0_ += ct_;                          \
            par_ ^= 1;                                                      \
            ixr_ += step8x;                                                 \
            iyr_ += step8y;                                                 \
        }                                                                   \
        acc0 += (float)a0_.x + (float)a1_.x;                                \
        acc1 += (float)a0_.y + (float)a1_.y;                                \
    }

    if (bh0 <= bh1) {
        // Initialize incremental bbox state for chunk bh0.
        {
            float ha = (float)bh0 - 255.5f;
            float hb = ha + (float)(KH - 1);
            ixmn = xlo_pair - fmaxf(s * ha, s * hb) + 255.5f;
            iymn = ylo_pair + fminf(c * ha, c * hb) + 255.5f;
            iymx = yhi_pair + fmaxf(c * ha, c * hb) + 255.5f;
        }

        int x4_0, yl_0, t4_0;
        int x4_1, yl_1, t4_1;

        // Prologue: stage chunk 0 into bufA.
        BBOX2(bh0, x4_0, yl_0, t4_0);
        STAGE(bufA, x4_0, yl_0, t4_0);
        __syncthreads();                       // compiler drains vmcnt here

        for (int hc = bh0; hc <= bh1; hc += 2 * KH) {
            int hc1 = hc + KH;
            if (hc1 <= bh1) {
                BBOX2(hc1, x4_1, yl_1, t4_1);
                STAGE(bufB, x4_1, yl_1, t4_1);
            }
            GATHER(bufA, hc, x4_0, yl_0);
            __syncthreads();                   // bufB ready; bufA free

            if (hc1 <= bh1) {
                int hc2 = hc + 2 * KH;
                if (hc2 <= bh1) {
                    BBOX2(hc2, x4_0, yl_0, t4_0);
                    STAGE(bufA, x4_0, yl_0, t4_0);
                }
                GATHER(bufB, hc1, x4_1, yl_1);
                __syncthreads();               // bufA ready; bufB free
            }
        }
    }

    // Reduce the 8 phase partials for both batches, reusing bufA.
    __syncthreads();
    bufA[(p << 6) + lane] = __float_as_uint(acc0);
    bufA[512 + (p << 6) + lane] = __float_as_uint(acc1);
    __syncthreads();
    if (p < 2) {                 // wave 0 -> batch 0, wave 1 -> batch 1
        const unsigned* base = bufA + (p << 9);
        float r = 0.0f;
        #pragma unroll
        for (int q = 0; q < 8; ++q) r += __uint_as_float(base[(q << 6) + lane]);
        size_t o = (size_t)w * VIEWS + v;
        out[o + (size_t)p * IMGSZ * VIEWS] = r * 0.5f;
    }
}

extern "C" void kernel_launch(void* const* d_in, const int* in_sizes, int n_in,
                              void* d_out, int out_size, void* d_ws, size_t ws_size,
                              hipStream_t stream) {
    const float* x = (const float*)d_in[0];
    float* out = (float*)d_out;
    unsigned* padq = (unsigned*)d_ws;   // PH*PW*4 = 2,004,992 bytes

    constexpr int padTotal = PH * (PW / 4);          // 125312 groups
    pad_kernel<<<(padTotal + 255) / 256, 256, 0, stream>>>(x, padq);

    int nblocks = VIEWS * (IMGSZ / WCHUNK);          // 2880
    fp_kernel<<<nblocks, NT, 0, stream>>>(padq, out);
}

// Round 15
// 150.399 us; speedup vs baseline: 1.2075x; 1.2075x over previous
//
#include <hip/hip_runtime.h>

typedef __fp16 h2 __attribute__((ext_vector_type(2)));

constexpr int VIEWS = 360;
constexpr int IMGSZ = 512;
constexpr int WCHUNK = 64;   // w per block
constexpr int KH = 64;       // h per LDS chunk
constexpr int PITCH = 101;   // odd pitch (conflict-free reads; 2-way floor benign)
constexpr int MAXNY = 94;    // max staged rows (validated geometry)
constexpr int LDSDW = PITCH * MAXNY;   // 9494 dw = 37976 B -> 4 blocks/CU
constexpr int PW = 712;      // padded width (dword positions per row)
constexpr int PH = 704;      // padded height
constexpr int PAD = 96;
constexpr int RJOBS = 96;    // padded row-job space (>= MAXNY)
constexpr int KJOBS = 25;    // 16B groups per row (100 dwords)
constexpr int NIT = (RJOBS * KJOBS + 255) / 256;   // 10

// ---------- pad kernel: zero-padded, BATCH-PACKED f16 texels ---------------
// padq[py][px] = (f16 img_b0[py-PAD][px-PAD], f16 img_b1[py-PAD][px-PAD])
__global__ __launch_bounds__(256) void pad_kernel(const float* __restrict__ x,
                                                  unsigned* __restrict__ padq) {
    constexpr int PW4 = PW / 4;              // 178 groups per row
    constexpr int total = PH * PW4;          // 125312 groups
    int idx = blockIdx.x * 256 + threadIdx.x;
    if (idx >= total) return;
    int py = idx / PW4;
    int px4 = idx - py * PW4;
    int gx = px4 * 4 - PAD;                  // multiple of 4
    int gy = py - PAD;
    const float* img0 = x;
    const float* img1 = x + (size_t)IMGSZ * IMGSZ;
    float4 a = make_float4(0.f, 0.f, 0.f, 0.f);
    float4 bq = a;
    if ((unsigned)gy < (unsigned)IMGSZ && (unsigned)gx < (unsigned)IMGSZ) {
        size_t off = (size_t)gy * IMGSZ + gx;    // gx%4==0 -> all-in/all-out
        a  = *(const float4*)(img0 + off);
        bq = *(const float4*)(img1 + off);
    }
    uint4 d;
    d.x = __builtin_bit_cast(unsigned, __builtin_amdgcn_cvt_pkrtz(a.x, bq.x));
    d.y = __builtin_bit_cast(unsigned, __builtin_amdgcn_cvt_pkrtz(a.y, bq.y));
    d.z = __builtin_bit_cast(unsigned, __builtin_amdgcn_cvt_pkrtz(a.z, bq.z));
    d.w = __builtin_bit_cast(unsigned, __builtin_amdgcn_cvt_pkrtz(a.w, bq.w));
    *(uint4*)&padq[(size_t)idx * 4] = d;
}

// ---------- main kernel: R6 (best-measured) + float-domain addressing ------
__global__ __launch_bounds__(256, 4) void fp_kernel(const unsigned* __restrict__ padq,
                                                    float* __restrict__ out) {
    __shared__ __align__(16) unsigned tileU[LDSDW];

    int blk = blockIdx.x;          // 2880 = VIEWS * 8
    int wc = blk & 7;
    int v = blk >> 3;

    int tid = threadIdx.x;
    int lane = tid & 63;
    int g = tid >> 6;              // h phase 0..3
    int w = wc * WCHUNK + lane;

    double ang = -3.14159265358979323846 * (double)(v + 1) / (double)VIEWS
                 - 3.14159265358979323846;
    float c = (float)cos(ang);
    float s = (float)sin(ang);

    float xw = (float)w + 0.5f - 256.0f;
    float cxw = fmaf(c, xw, 255.5f);
    float sxw = fmaf(s, xw, 255.5f);

    // Per-thread valid-h interval (validated rounds 0-13).
    float lo = -1e30f, hi = 1e30f;
    {
        float coef = -s, base = cxw;
        if (fabsf(coef) > 1e-6f) {
            float a = (-1.0f - base) / coef;
            float bq = (512.0f - base) / coef;
            lo = fmaxf(lo, fminf(a, bq));
            hi = fminf(hi, fmaxf(a, bq));
        } else if (!(base > -1.0f && base < 512.0f)) {
            lo = 1e30f; hi = -1e30f;
        }
    }
    {
        float coef = c, base = sxw;
        if (fabsf(coef) > 1e-6f) {
            float a = (-1.0f - base) / coef;
            float bq = (512.0f - base) / coef;
            lo = fmaxf(lo, fminf(a, bq));
            hi = fminf(hi, fmaxf(a, bq));
        } else if (!(base > -1.0f && base < 512.0f)) {
            lo = 1e30f; hi = -1e30f;
        }
    }
    float h0f = fminf(fmaxf(floorf(lo + 255.5f) - 1.0f, 0.0f), 512.0f);
    float h1f = fminf(fmaxf(ceilf(hi + 255.5f) + 1.0f, -1.0f), 511.0f);
    int h0 = (int)h0f;
    int h1 = (int)h1f;

    int bh0 = h0, bh1 = h1;
    #pragma unroll
    for (int m = 1; m < 64; m <<= 1) {
        bh0 = min(bh0, __shfl_xor(bh0, m, 64));
        bh1 = max(bh1, __shfl_xor(bh1, m, 64));
    }

    float xa = (float)(wc * WCHUNK) + 0.5f - 256.0f;
    float xb = xa + 63.0f;

    float acc0 = 0.0f, acc1 = 0.0f;
    float step4x = -4.0f * s;
    float step4y = 4.0f * c;

    for (int hc = bh0; hc <= bh1; hc += KH) {
        int hend = min(hc + KH - 1, bh1);

        float ha = (float)hc - 255.5f;
        float hb = (float)hend - 255.5f;
        float ix00 = c * xa - s * ha, ix01 = c * xa - s * hb;
        float ix10 = c * xb - s * ha, ix11 = c * xb - s * hb;
        float iy00 = s * xa + c * ha, iy01 = s * xa + c * hb;
        float iy10 = s * xb + c * ha, iy11 = s * xb + c * hb;
        float ixmn = fminf(fminf(ix00, ix01), fminf(ix10, ix11)) + 255.5f;
        float iymn = fminf(fminf(iy00, iy01), fminf(iy10, iy11)) + 255.5f;
        float iymx = fmaxf(fmaxf(iy00, iy01), fmaxf(iy10, iy11)) + 255.5f;
        int x_lo = (int)floorf(ixmn) - 1;
        int x_lo4 = x_lo & ~3;
        int y_lo = (int)floorf(iymn) - 1;
        int NY = min((int)floorf(iymx) + 3 - y_lo, MAXNY);

        __syncthreads();

        // R6-validated staging: job j -> (row r = j mod 96, group k = j/96).
        // Consecutive lanes write consecutive ROWS (addr stride 101 dw, odd)
        // -> LDS writes conflict-free. Clamped duplicates are benign.
        {
            const unsigned* pb = padq + (y_lo + PAD) * PW + (x_lo4 + PAD);
            uint4 vals[NIT];
            #pragma unroll
            for (int it = 0; it < NIT; ++it) {
                int j = min(it * 256 + tid, RJOBS * KJOBS - 1);
                int k = j / RJOBS;             // 0..24 (const magic-div)
                int r = j - k * RJOBS;         // 0..95
                int rr = min(r, NY - 1);
                vals[it] = *(const uint4*)(pb + rr * PW + (k << 2));
            }
            #pragma unroll
            for (int it = 0; it < NIT; ++it) {
                int j = min(it * 256 + tid, RJOBS * KJOBS - 1);
                int k = j / RJOBS;
                int r = j - k * RJOBS;
                int rr = min(r, NY - 1);
                int base = rr * PITCH + (k << 2);
                tileU[base + 0] = vals[it].x;
                tileU[base + 1] = vals[it].y;
                tileU[base + 2] = vals[it].z;
                tileU[base + 3] = vals[it].w;
            }
        }
        __syncthreads();

        // Gather: 2 x ds_read2_b32 per sample; packed-f16 lerp serves both
        // batches. Float-domain addressing (byte = ty*404 + tx*4, exact:
        // integers < 2^24) -- removes the quarter-rate v_mul_lo_u32.
        // In-tile coords strictly positive -> trunc == floor.
        float hh0 = (float)(hc + g) - 255.5f;
        float ixr = fmaf(-s, hh0, cxw) - (float)x_lo4;
        float iyr = fmaf(c, hh0, sxw) - (float)y_lo;
        h2 accp0 = (h2)0.0f;
        h2 accp1 = (h2)0.0f;
        int parity = 0;
        #pragma unroll 8
        for (int h = hc + g; h <= hend; h += 4) {
            float tx = truncf(ixr);
            float ty = truncf(iyr);
            float wx1 = ixr - tx;
            float wy1 = iyr - ty;
            h2 wxs = __builtin_amdgcn_cvt_pkrtz(wx1, wx1);
            h2 wys = __builtin_amdgcn_cvt_pkrtz(wy1, wy1);
            unsigned a = (unsigned)fmaf(ty, 404.0f, tx * 4.0f);
            const unsigned* p = (const unsigned*)((const char*)tileU + a);
            h2 t00 = __builtin_bit_cast(h2, p[0]);
            h2 t01 = __builtin_bit_cast(h2, p[1]);
            h2 t10 = __builtin_bit_cast(h2, p[PITCH]);
            h2 t11 = __builtin_bit_cast(h2, p[PITCH + 1]);
            h2 r0 = t00 + (t01 - t00) * wxs;
            h2 r1 = t10 + (t11 - t10) * wxs;
            h2 contrib = r0 + (r1 - r0) * wys;
            if (parity) accp1 += contrib; else accp0 += contrib;
            parity ^= 1;
            ixr += step4x;
            iyr += step4y;
        }
        acc0 += (float)accp0.x + (float)accp1.x;
        acc1 += (float)accp0.y + (float)accp1.y;
    }

    // Reduce the 4 h-phase partials for both batches, reusing the tile.
    __syncthreads();
    tileU[(g << 6) + lane] = __float_as_uint(acc0);
    tileU[256 + (g << 6) + lane] = __float_as_uint(acc1);
    __syncthreads();
    if (g == 0) {
        float r0 = __uint_as_float(tileU[lane]) + __uint_as_float(tileU[64 + lane]) +
                   __uint_as_float(tileU[128 + lane]) + __uint_as_float(tileU[192 + lane]);
        float r1 = __uint_as_float(tileU[256 + lane]) + __uint_as_float(tileU[320 + lane]) +
                   __uint_as_float(tileU[384 + lane]) + __uint_as_float(tileU[448 + lane]);
        size_t o = (size_t)w * VIEWS + v;
        out[o] = r0 * 0.5f;
        out[(size_t)IMGSZ * VIEWS + o] = r1 * 0.5f;
    }
}

extern "C" void kernel_launch(void* const* d_in, const int* in_sizes, int n_in,
                              void* d_out, int out_size, void* d_ws, size_t ws_size,
                              hipStream_t stream) {
    const float* x = (const float*)d_in[0];
    float* out = (float*)d_out;
    unsigned* padq = (unsigned*)d_ws;   // PH*PW*4 = 2,004,992 bytes

    constexpr int padTotal = PH * (PW / 4);          // 125312 groups
    pad_kernel<<<(padTotal + 255) / 256, 256, 0, stream>>>(x, padq);

    int nblocks = VIEWS * (IMGSZ / WCHUNK);          // 2880
    fp_kernel<<<nblocks, 256, 0, stream>>>(padq, out);
}